// Round 3
// baseline (423.813 us; speedup 1.0000x reference)
//
#include <hip/hip_runtime.h>
#include <math.h>

// NetNew_17162689315115: 8-layer EQL-style net, B=524288 rows.
// Reference is numpy float64; chaotic map (sin/cos at |z|~1e8-1e14) -> ENTIRE
// chain in fp64, bitwise-frozen since R3 (absmax 1245184 / thr 1646264).
// DO NOT reassociate: each z[j] = fma(W[j,k], h[k], acc) ascending k.
//
// Evidence log:
//  R4 407us (fp64 weights pre-widened to d_ws). R5/R6 allocator hints:
//  regress badly — do not reintroduce. R7 block 64 vs 256: neutral.
//  R8 j-blocking: exactly neutral -> "spills" are AGPR moves (unified file:
//  ~112 arch VGPR + ~112 AGPR = 224 total -> 2 waves/SIMD hard cap).
//  R9 I$ shrink (rolled j-loop + shared noinline transcendentals):
//  407 -> 222us, busy 265 -> 127us. Straight-line code streams through I$
//  with ~zero reuse -> code bytes are precious.
//  R10 merged transcendental calls: ~neutral.
//  R11 inline exp/log, shared noinline sincos, j-unroll 2: 222 -> 214us
//  (VALUBusy 56%, occupancy 22.7% == 2 waves/SIMD, HBM 0.6%).
//  R12 LDS h-split + launch_bounds(64,3): 604us REGRESSION — 3-wave corridor
//  (85 reg + 26 LDS doubles) can't hold live set (~118); 21 dbl/thread
//  scratch spill (WRITE_SIZE 2->90MB). 2 waves/SIMD is structural. CLOSED.
//  R13 j-unroll 4: 244us REGRESSION, VALUBusy 45% — I$ streaming again
//  (+5KB matmul code). Dep-chain-latency theory REFUTED (busy didn't rise).
//  Unroll 2 is the code-size sweet spot. CLOSED.
// R14: weight-fetch latency theory. 33.5KB of fp64 W per wave-pass via
// s_load streams through the ~16KB sK$ with zero reuse: ~524 line misses x
// ~200cyc L2 latency, pipeline depth capped by the 112-SGPR file. Idle
// arithmetic: 93us/8 passes = ~28Kcyc/pass idle vs 524 x ~50cyc exposed =
// ~26Kcyc. Fix: stage ALL weights into LDS once per block (double2 burst +
// one barrier); weight reads become uniform-address ds_read (broadcast,
// conflict-free, pipelined on DS pipe alongside VALU). LDS 33.5KB/block x
// 2 blocks/CU = 67KB < 160KB -> occupancy unchanged. Bitwise-neutral:
// same fp64 values, same op order.

static constexpr double MAX_MLT   = 99999999.0;
static constexpr double MAX_DIV   = 9999.0;
static constexpr double MAX_EXP_C = 17.0;
static constexpr double MIN_DENOM = 0.0001;

static constexpr int IN0  = 8;   // vari_num + const_num
static constexpr int VDIM = 13;  // rows of each W
static constexpr int NOPS = 9;   // ops appended per layer
static constexpr int FDIM = 80;  // final h dim: 8 + 8*9
static constexpr int WTOT = 4188; // total fp64 weight elements (incl. Wf)

// layer weight element counts and fp64 workspace offsets
// in_dims: 8,17,26,35,44,53,62,71 ; W_i is 13 x in_dim ; Wf is 1 x 80
static constexpr int WSZ[9]  = {104, 221, 338, 455, 572, 689, 806, 923, 80};
static constexpr int WOFF[9] = {0, 104, 325, 663, 1118, 1690, 2379, 3185, 4108};

// ---- prep: widen fp32 weights -> fp64 workspace (exact, bitwise-neutral) ----
__global__ void widen_kernel(const float* __restrict__ s0, const float* __restrict__ s1,
                             const float* __restrict__ s2, const float* __restrict__ s3,
                             const float* __restrict__ s4, const float* __restrict__ s5,
                             const float* __restrict__ s6, const float* __restrict__ s7,
                             const float* __restrict__ s8, double* __restrict__ dst) {
    int seg = blockIdx.y;
    int i   = blockIdx.x * blockDim.x + threadIdx.x;
    const float* src;
    switch (seg) {
        case 0: src = s0; break; case 1: src = s1; break; case 2: src = s2; break;
        case 3: src = s3; break; case 4: src = s4; break; case 5: src = s5; break;
        case 6: src = s6; break; case 7: src = s7; break; default: src = s8; break;
    }
    if (i < WSZ[seg]) dst[WOFF[seg] + i] = (double)src[i];
}

// ---- one shared body for the two PH-heavy (branchy) functions ----
struct D2 { double s, c; };
__device__ __attribute__((noinline))
D2 d_sincos2(double as, double ac) {
    D2 r;
    r.s = sin(as);
    r.c = cos(ac);
    return r;
}

// _clip_mag forward, float64: scale = |mx/v|, o = where(|v|>=mx, v*scale, v).
// NaN passes through (compare false), matching jnp.where.
__device__ __forceinline__ double clip_ref(double v, double mx) {
    double scale = fabs(mx / v);
    double vs    = v * scale;
    return (fabs(v) >= mx) ? vs : v;
}

template<int IN_DIM, int BASE>
__device__ __forceinline__ void layer_step(const double* __restrict__ W,
                                           double (&h)[FDIM]) {
    double z[VDIM];
    // Rolled j-loop, unroll 2 (R13: unroll 4 regresses via I$ streaming).
    // Each z[j] is the same ascending-k fma chain as the fully-unrolled form
    // -> bitwise equal. k stays unrolled so every h index is compile-time
    // constant (register/AGPR-resident). W now points into LDS: uniform-addr
    // ds_read broadcast, contiguous in k -> compiler merges to b128.
    #pragma unroll 2
    for (int j = 0; j < VDIM; ++j) {
        const double* Wr = W + j * IN_DIM;
        double acc = 0.0;
        #pragma unroll
        for (int k = 0; k < IN_DIM; ++k) {
            acc = fma(Wr[k], h[BASE + k], acc);  // frozen accum order
        }
        z[j] = acc;
    }
    constexpr int BO = BASE - NOPS;
    // op order: + - * / sin cos exp log square, consuming z cols in order
    h[BO + 0] = z[0] + z[1];
    h[BO + 1] = z[2] - z[3];
    h[BO + 2] = clip_ref(z[4] * z[5], MAX_MLT);
    {
        double b     = z[7];
        double denom = (b == 0.0) ? (b + MIN_DENOM) : b;
        h[BO + 3]    = clip_ref(z[6] / denom, MAX_DIV);
    }
    {
        D2 t = d_sincos2(z[8], z[9]);   // shared noinline: PH-heavy bodies
        h[BO + 4] = t.s;
        h[BO + 5] = t.c;
    }
    {
        double a    = z[10];
        double safe = (a >= MAX_EXP_C) ? (a * (MAX_EXP_C / a)) : a;
        h[BO + 6]   = exp(safe);        // inlined: branch-light, schedules in
    }
    h[BO + 7] = log(fabs(z[11]));       // inlined: branch-light
    h[BO + 8] = clip_ref(z[12] * z[12], MAX_MLT);
}

__global__ void __launch_bounds__(64)
net_kernel(const float* __restrict__ x, const double* __restrict__ Wd,
           float* __restrict__ out, int nrows) {
    // Stage ALL weights into LDS: 4188 doubles = 33504 B. 2 blocks/CU ->
    // 67KB of 160KB. Cooperative double2 burst: 2094 16B units, 64 threads.
    __shared__ double Wl[WTOT];
    {
        const double2* src = reinterpret_cast<const double2*>(Wd);
        double2*       dst = reinterpret_cast<double2*>(Wl);
        int tid = threadIdx.x;
        #pragma unroll
        for (int w = 0; w < WTOT / 2 / 64; ++w)          // 32 full rounds
            dst[tid + w * 64] = src[tid + w * 64];
        if (tid < (WTOT / 2) % 64)                        // tail: 46 units
            dst[tid + (WTOT / 2 / 64) * 64] = src[tid + (WTOT / 2 / 64) * 64];
    }
    __syncthreads();

    int row = blockIdx.x * blockDim.x + threadIdx.x;
    if (row >= nrows) return;

    double h[FDIM];

    // x occupies the TAIL of the final feature vector (each layer prepends).
    const float4* x4 = reinterpret_cast<const float4*>(x);
    float4 xa = x4[row * 2 + 0];
    float4 xb = x4[row * 2 + 1];
    h[72] = (double)xa.x; h[73] = (double)xa.y; h[74] = (double)xa.z; h[75] = (double)xa.w;
    h[76] = (double)xb.x; h[77] = (double)xb.y; h[78] = (double)xb.z; h[79] = (double)xb.w;

    layer_step<IN0 + 0 * NOPS, 72>(Wl + WOFF[0], h);  // in_dim  8, write at 63
    layer_step<IN0 + 1 * NOPS, 63>(Wl + WOFF[1], h);  // in_dim 17, write at 54
    layer_step<IN0 + 2 * NOPS, 54>(Wl + WOFF[2], h);  // in_dim 26, write at 45
    layer_step<IN0 + 3 * NOPS, 45>(Wl + WOFF[3], h);  // in_dim 35, write at 36
    layer_step<IN0 + 4 * NOPS, 36>(Wl + WOFF[4], h);  // in_dim 44, write at 27
    layer_step<IN0 + 5 * NOPS, 27>(Wl + WOFF[5], h);  // in_dim 53, write at 18
    layer_step<IN0 + 6 * NOPS, 18>(Wl + WOFF[6], h);  // in_dim 62, write at  9
    layer_step<IN0 + 7 * NOPS,  9>(Wl + WOFF[7], h);  // in_dim 71, write at  0

    // Final dot stays unrolled: h indices must remain static (any dynamic h
    // access would force the whole array to scratch).
    const double* Wf = Wl + WOFF[8];
    double acc = 0.0;
    #pragma unroll
    for (int k = 0; k < FDIM; ++k) {
        acc = fma(Wf[k], h[k], acc);
    }
    out[row] = (float)acc;
}

extern "C" void kernel_launch(void* const* d_in, const int* in_sizes, int n_in,
                              void* d_out, int out_size, void* d_ws, size_t ws_size,
                              hipStream_t stream) {
    const float* x = (const float*)d_in[0];
    double* Wd     = (double*)d_ws;   // 4188 doubles = 33.5 KB
    float* out     = (float*)d_out;

    // widen weights (d_ws is re-poisoned before every call -> must rewrite)
    {
        dim3 grid((923 + 255) / 256, 9);
        widen_kernel<<<grid, 256, 0, stream>>>(
            (const float*)d_in[1], (const float*)d_in[2], (const float*)d_in[3],
            (const float*)d_in[4], (const float*)d_in[5], (const float*)d_in[6],
            (const float*)d_in[7], (const float*)d_in[8], (const float*)d_in[9],
            Wd);
    }

    int nrows = in_sizes[0] / IN0;
    int block = 64;
    int grid  = (nrows + block - 1) / block;
    net_kernel<<<grid, block, 0, stream>>>(x, Wd, out, nrows);
}

// Round 4
// 310.354 us; speedup vs baseline: 1.3656x; 1.3656x over previous
//
#include <hip/hip_runtime.h>
#include <math.h>

// NetNew_17162689315115: 8-layer EQL-style net, B=524288 rows.
// Reference is numpy float64; chaotic map (sin/cos at |z|~1e8-1e14) -> ENTIRE
// chain in fp64, bitwise-frozen since R3 (absmax 1245184 / thr 1646264).
// DO NOT reassociate: each z[j] = fma(W[j,k], h[k], acc) ascending k.
//
// Evidence log:
//  R4 407us (fp64 weights pre-widened to d_ws). R5/R6 allocator hints:
//  regress badly — do not reintroduce. R7 block 64 vs 256: neutral.
//  R8 j-blocking: exactly neutral -> unified file ~224 regs -> 2 waves/SIMD.
//  R9 I$ shrink (rolled j-loop + shared noinline transcendentals):
//  407 -> 222us. Straight-line code streams I$ with ~zero reuse.
//  R10 merged transcendental calls: ~neutral.
//  R11 inline exp/log, shared noinline sincos, j-unroll 2: 222 -> 214us
//  (VALUBusy 56%, occupancy 22.7% == 2 waves/SIMD, HBM 0.6%).
//  R12 LDS h-split + launch_bounds(64,3): 604us REGRESSION — live set
//  can't fit 3-wave corridor; scratch spill. Occupancy axis CLOSED.
//  R13 j-unroll 4: 244us REGRESSION (I$ streaming). Unroll 2 sweet spot.
//  R14 W->LDS with 64-thread blocks: 369us. NOT a refutation of staging:
//  1-wave blocks need 8 blocks/CU for 2 waves/SIMD, but 8x33.5KB > 160KB
//  -> LDS capped at 4 blocks/CU = 1 wave/SIMD (occ 11.6%). KEY SIGNAL:
//  per-wave issue efficiency ROSE 28% -> 34% with LDS weights — the
//  weight-fetch-stall theory is alive.
// R15: same staging, block=256 (4 waves SHARE one 33.5KB copy). Resident:
// 2 blocks/CU (VGPR-capped) = 8 waves/CU = 2 waves/SIMD, LDS 67KB < 160KB
// -> LDS caps nothing. R7: block size otherwise neutral. Bitwise-neutral.

static constexpr double MAX_MLT   = 99999999.0;
static constexpr double MAX_DIV   = 9999.0;
static constexpr double MAX_EXP_C = 17.0;
static constexpr double MIN_DENOM = 0.0001;

static constexpr int IN0  = 8;   // vari_num + const_num
static constexpr int VDIM = 13;  // rows of each W
static constexpr int NOPS = 9;   // ops appended per layer
static constexpr int FDIM = 80;  // final h dim: 8 + 8*9
static constexpr int WTOT = 4188; // total fp64 weight elements (incl. Wf)
static constexpr int BDIM = 256;  // 4 waves share one LDS weight copy

// layer weight element counts and fp64 workspace offsets
// in_dims: 8,17,26,35,44,53,62,71 ; W_i is 13 x in_dim ; Wf is 1 x 80
static constexpr int WSZ[9]  = {104, 221, 338, 455, 572, 689, 806, 923, 80};
static constexpr int WOFF[9] = {0, 104, 325, 663, 1118, 1690, 2379, 3185, 4108};

// ---- prep: widen fp32 weights -> fp64 workspace (exact, bitwise-neutral) ----
__global__ void widen_kernel(const float* __restrict__ s0, const float* __restrict__ s1,
                             const float* __restrict__ s2, const float* __restrict__ s3,
                             const float* __restrict__ s4, const float* __restrict__ s5,
                             const float* __restrict__ s6, const float* __restrict__ s7,
                             const float* __restrict__ s8, double* __restrict__ dst) {
    int seg = blockIdx.y;
    int i   = blockIdx.x * blockDim.x + threadIdx.x;
    const float* src;
    switch (seg) {
        case 0: src = s0; break; case 1: src = s1; break; case 2: src = s2; break;
        case 3: src = s3; break; case 4: src = s4; break; case 5: src = s5; break;
        case 6: src = s6; break; case 7: src = s7; break; default: src = s8; break;
    }
    if (i < WSZ[seg]) dst[WOFF[seg] + i] = (double)src[i];
}

// ---- one shared body for the two PH-heavy (branchy) functions ----
struct D2 { double s, c; };
__device__ __attribute__((noinline))
D2 d_sincos2(double as, double ac) {
    D2 r;
    r.s = sin(as);
    r.c = cos(ac);
    return r;
}

// _clip_mag forward, float64: scale = |mx/v|, o = where(|v|>=mx, v*scale, v).
// NaN passes through (compare false), matching jnp.where.
__device__ __forceinline__ double clip_ref(double v, double mx) {
    double scale = fabs(mx / v);
    double vs    = v * scale;
    return (fabs(v) >= mx) ? vs : v;
}

template<int IN_DIM, int BASE>
__device__ __forceinline__ void layer_step(const double* __restrict__ W,
                                           double (&h)[FDIM]) {
    double z[VDIM];
    // Rolled j-loop, unroll 2 (R13: unroll 4 regresses via I$ streaming).
    // Each z[j] is the same ascending-k fma chain as the fully-unrolled form
    // -> bitwise equal. k stays unrolled so every h index is compile-time
    // constant (register/AGPR-resident). W points into LDS: uniform-addr
    // ds_read broadcast, contiguous in k -> compiler merges to b128.
    #pragma unroll 2
    for (int j = 0; j < VDIM; ++j) {
        const double* Wr = W + j * IN_DIM;
        double acc = 0.0;
        #pragma unroll
        for (int k = 0; k < IN_DIM; ++k) {
            acc = fma(Wr[k], h[BASE + k], acc);  // frozen accum order
        }
        z[j] = acc;
    }
    constexpr int BO = BASE - NOPS;
    // op order: + - * / sin cos exp log square, consuming z cols in order
    h[BO + 0] = z[0] + z[1];
    h[BO + 1] = z[2] - z[3];
    h[BO + 2] = clip_ref(z[4] * z[5], MAX_MLT);
    {
        double b     = z[7];
        double denom = (b == 0.0) ? (b + MIN_DENOM) : b;
        h[BO + 3]    = clip_ref(z[6] / denom, MAX_DIV);
    }
    {
        D2 t = d_sincos2(z[8], z[9]);   // shared noinline: PH-heavy bodies
        h[BO + 4] = t.s;
        h[BO + 5] = t.c;
    }
    {
        double a    = z[10];
        double safe = (a >= MAX_EXP_C) ? (a * (MAX_EXP_C / a)) : a;
        h[BO + 6]   = exp(safe);        // inlined: branch-light, schedules in
    }
    h[BO + 7] = log(fabs(z[11]));       // inlined: branch-light
    h[BO + 8] = clip_ref(z[12] * z[12], MAX_MLT);
}

__global__ void __launch_bounds__(BDIM)
net_kernel(const float* __restrict__ x, const double* __restrict__ Wd,
           float* __restrict__ out, int nrows) {
    // Stage ALL weights into LDS once per 256-thread block (4 waves share).
    // 4188 doubles = 33504 B; 2 blocks/CU resident -> 67KB of 160KB.
    __shared__ double Wl[WTOT];
    {
        const double2* src = reinterpret_cast<const double2*>(Wd);
        double2*       dst = reinterpret_cast<double2*>(Wl);
        int tid = threadIdx.x;
        #pragma unroll
        for (int w = 0; w < (WTOT / 2) / BDIM; ++w)       // 8 full rounds
            dst[tid + w * BDIM] = src[tid + w * BDIM];
        if (tid < (WTOT / 2) % BDIM)                       // tail: 46 units
            dst[tid + ((WTOT / 2) / BDIM) * BDIM] =
            src[tid + ((WTOT / 2) / BDIM) * BDIM];
    }
    __syncthreads();

    int row = blockIdx.x * blockDim.x + threadIdx.x;
    if (row >= nrows) return;

    double h[FDIM];

    // x occupies the TAIL of the final feature vector (each layer prepends).
    const float4* x4 = reinterpret_cast<const float4*>(x);
    float4 xa = x4[row * 2 + 0];
    float4 xb = x4[row * 2 + 1];
    h[72] = (double)xa.x; h[73] = (double)xa.y; h[74] = (double)xa.z; h[75] = (double)xa.w;
    h[76] = (double)xb.x; h[77] = (double)xb.y; h[78] = (double)xb.z; h[79] = (double)xb.w;

    layer_step<IN0 + 0 * NOPS, 72>(Wl + WOFF[0], h);  // in_dim  8, write at 63
    layer_step<IN0 + 1 * NOPS, 63>(Wl + WOFF[1], h);  // in_dim 17, write at 54
    layer_step<IN0 + 2 * NOPS, 54>(Wl + WOFF[2], h);  // in_dim 26, write at 45
    layer_step<IN0 + 3 * NOPS, 45>(Wl + WOFF[3], h);  // in_dim 35, write at 36
    layer_step<IN0 + 4 * NOPS, 36>(Wl + WOFF[4], h);  // in_dim 44, write at 27
    layer_step<IN0 + 5 * NOPS, 27>(Wl + WOFF[5], h);  // in_dim 53, write at 18
    layer_step<IN0 + 6 * NOPS, 18>(Wl + WOFF[6], h);  // in_dim 62, write at  9
    layer_step<IN0 + 7 * NOPS,  9>(Wl + WOFF[7], h);  // in_dim 71, write at  0

    // Final dot stays unrolled: h indices must remain static (any dynamic h
    // access would force the whole array to scratch).
    const double* Wf = Wl + WOFF[8];
    double acc = 0.0;
    #pragma unroll
    for (int k = 0; k < FDIM; ++k) {
        acc = fma(Wf[k], h[k], acc);
    }
    out[row] = (float)acc;
}

extern "C" void kernel_launch(void* const* d_in, const int* in_sizes, int n_in,
                              void* d_out, int out_size, void* d_ws, size_t ws_size,
                              hipStream_t stream) {
    const float* x = (const float*)d_in[0];
    double* Wd     = (double*)d_ws;   // 4188 doubles = 33.5 KB
    float* out     = (float*)d_out;

    // widen weights (d_ws is re-poisoned before every call -> must rewrite)
    {
        dim3 grid((923 + 255) / 256, 9);
        widen_kernel<<<grid, 256, 0, stream>>>(
            (const float*)d_in[1], (const float*)d_in[2], (const float*)d_in[3],
            (const float*)d_in[4], (const float*)d_in[5], (const float*)d_in[6],
            (const float*)d_in[7], (const float*)d_in[8], (const float*)d_in[9],
            Wd);
    }

    int nrows = in_sizes[0] / IN0;
    int block = BDIM;
    int grid  = (nrows + block - 1) / block;
    net_kernel<<<grid, block, 0, stream>>>(x, Wd, out, nrows);
}

// Round 5
// 296.969 us; speedup vs baseline: 1.4271x; 1.0451x over previous
//
#include <hip/hip_runtime.h>
#include <math.h>

// NetNew_17162689315115: 8-layer EQL-style net, B=524288 rows.
// Reference is numpy float64; chaotic map (sin/cos at |z|~1e8-1e14) -> ENTIRE
// chain in fp64, bitwise-frozen since R3 (absmax 1245184 / thr 1646264).
// DO NOT reassociate: each z[j] = fma(W[j,k], h[k], acc) ascending k.
//
// Evidence log:
//  R4 407us (fp64 weights pre-widened to d_ws). R5/R6 allocator hints:
//  regress badly — do not reintroduce. R7 block 64 vs 256: neutral.
//  R8 j-blocking: exactly neutral -> unified file ~224 regs -> 2 waves/SIMD.
//  R9 I$ shrink (rolled j-loop + shared noinline transcendentals):
//  407 -> 222us. Straight-line code streams I$ with ~zero reuse.
//  R10 merged transcendental calls: ~neutral.
//  R11 inline exp/log, shared noinline sincos, j-unroll 2: 222 -> 214us
//  (VALUBusy 56%, occupancy 22.7% == 2 waves/SIMD, HBM 0.6%).
//  R12 LDS h-split + launch_bounds(64,3): 604us REGRESSION — live set
//  can't fit 3-wave corridor; scratch spill. Occupancy axis CLOSED.
//  R13 j-unroll 4: 244us REGRESSION (I$ streaming). Unroll 2 sweet spot.
//  R14 W->LDS, 64-thr blocks: 369us (LDS capped occupancy at 1 wave/SIMD;
//  but per-wave issue efficiency ROSE 28%->34% -> weight-fetch stall real).
//  R15 W->LDS, 256-thr blocks (iso-occupancy 2 waves/SIMD): 261us, busy
//  ~equal to R11, MORE stall. LDS weight storage CLOSED: ds_read path adds
//  2094 dynamic instrs + lgkmcnt deps and loses free SGPR fma operands.
// R16: keep R11's s_load path; attack the MISS RATE instead. All waves read
// the SAME 33.5KB weight stream but drift to different layers -> ~16KB
// scalar K$ (per CU-pair) thrashes: ~524 line misses x ~200cyc, pipelined
// only 2-4 deep by the 112-SGPR file ~= the 28Kcyc/pass idle. Fix: block =
// 512 thr = 8 waves = entire CU residency (2x224=448<=512 VGPR/SIMD) +
// __syncthreads() per layer -> all waves on a CU stay in the SAME layer;
// working set <= 7.4KB (two drifted blocks on a K$ pair: <=13.8KB <= 16KB).
// First wave misses, other 7 hit. 8 barriers/pass << idle. 524288 = 1024*512
// exactly -> no tail; store predicated anyway. Bitwise-neutral.

static constexpr double MAX_MLT   = 99999999.0;
static constexpr double MAX_DIV   = 9999.0;
static constexpr double MAX_EXP_C = 17.0;
static constexpr double MIN_DENOM = 0.0001;

static constexpr int IN0  = 8;   // vari_num + const_num
static constexpr int VDIM = 13;  // rows of each W
static constexpr int NOPS = 9;   // ops appended per layer
static constexpr int FDIM = 80;  // final h dim: 8 + 8*9
static constexpr int BDIM = 512; // 8 waves = full CU residency, layer-locked

// layer weight element counts and fp64 workspace offsets
// in_dims: 8,17,26,35,44,53,62,71 ; W_i is 13 x in_dim ; Wf is 1 x 80
static constexpr int WSZ[9]  = {104, 221, 338, 455, 572, 689, 806, 923, 80};
static constexpr int WOFF[9] = {0, 104, 325, 663, 1118, 1690, 2379, 3185, 4108};

// ---- prep: widen fp32 weights -> fp64 workspace (exact, bitwise-neutral) ----
__global__ void widen_kernel(const float* __restrict__ s0, const float* __restrict__ s1,
                             const float* __restrict__ s2, const float* __restrict__ s3,
                             const float* __restrict__ s4, const float* __restrict__ s5,
                             const float* __restrict__ s6, const float* __restrict__ s7,
                             const float* __restrict__ s8, double* __restrict__ dst) {
    int seg = blockIdx.y;
    int i   = blockIdx.x * blockDim.x + threadIdx.x;
    const float* src;
    switch (seg) {
        case 0: src = s0; break; case 1: src = s1; break; case 2: src = s2; break;
        case 3: src = s3; break; case 4: src = s4; break; case 5: src = s5; break;
        case 6: src = s6; break; case 7: src = s7; break; default: src = s8; break;
    }
    if (i < WSZ[seg]) dst[WOFF[seg] + i] = (double)src[i];
}

// ---- one shared body for the two PH-heavy (branchy) functions ----
struct D2 { double s, c; };
__device__ __attribute__((noinline))
D2 d_sincos2(double as, double ac) {
    D2 r;
    r.s = sin(as);
    r.c = cos(ac);
    return r;
}

// _clip_mag forward, float64: scale = |mx/v|, o = where(|v|>=mx, v*scale, v).
// NaN passes through (compare false), matching jnp.where.
__device__ __forceinline__ double clip_ref(double v, double mx) {
    double scale = fabs(mx / v);
    double vs    = v * scale;
    return (fabs(v) >= mx) ? vs : v;
}

template<int IN_DIM, int BASE>
__device__ __forceinline__ void layer_step(const double* __restrict__ W,
                                           double (&h)[FDIM]) {
    double z[VDIM];
    // Rolled j-loop, unroll 2 (R13: unroll 4 regresses via I$ streaming).
    // Each z[j] is the same ascending-k fma chain as the fully-unrolled form
    // -> bitwise equal. k stays unrolled so every h index is compile-time
    // constant (register/AGPR-resident). W is wave-uniform -> s_load path,
    // weights feed v_fma_f64 as free SGPR operands.
    #pragma unroll 2
    for (int j = 0; j < VDIM; ++j) {
        const double* Wr = W + j * IN_DIM;
        double acc = 0.0;
        #pragma unroll
        for (int k = 0; k < IN_DIM; ++k) {
            acc = fma(Wr[k], h[BASE + k], acc);  // frozen accum order
        }
        z[j] = acc;
    }
    constexpr int BO = BASE - NOPS;
    // op order: + - * / sin cos exp log square, consuming z cols in order
    h[BO + 0] = z[0] + z[1];
    h[BO + 1] = z[2] - z[3];
    h[BO + 2] = clip_ref(z[4] * z[5], MAX_MLT);
    {
        double b     = z[7];
        double denom = (b == 0.0) ? (b + MIN_DENOM) : b;
        h[BO + 3]    = clip_ref(z[6] / denom, MAX_DIV);
    }
    {
        D2 t = d_sincos2(z[8], z[9]);   // shared noinline: PH-heavy bodies
        h[BO + 4] = t.s;
        h[BO + 5] = t.c;
    }
    {
        double a    = z[10];
        double safe = (a >= MAX_EXP_C) ? (a * (MAX_EXP_C / a)) : a;
        h[BO + 6]   = exp(safe);        // inlined: branch-light, schedules in
    }
    h[BO + 7] = log(fabs(z[11]));       // inlined: branch-light
    h[BO + 8] = clip_ref(z[12] * z[12], MAX_MLT);
}

__global__ void __launch_bounds__(BDIM)
net_kernel(const float* __restrict__ x, const double* __restrict__ Wd,
           float* __restrict__ out, int nrows) {
    int row    = blockIdx.x * blockDim.x + threadIdx.x;
    bool active = row < nrows;
    int rowc   = active ? row : (nrows - 1);  // clamp: keeps loads in-bounds
    // (B = 524288 = 1024 * 512 -> no tail in practice; all threads active.)

    double h[FDIM];

    // x occupies the TAIL of the final feature vector (each layer prepends).
    const float4* x4 = reinterpret_cast<const float4*>(x);
    float4 xa = x4[rowc * 2 + 0];
    float4 xb = x4[rowc * 2 + 1];
    h[72] = (double)xa.x; h[73] = (double)xa.y; h[74] = (double)xa.z; h[75] = (double)xa.w;
    h[76] = (double)xb.x; h[77] = (double)xb.y; h[78] = (double)xb.z; h[79] = (double)xb.w;

    // Layer-lock the block's 8 waves (= entire CU residency): between
    // barriers, all waves s_load the SAME <=7.4KB weight slice -> scalar K$
    // hits for 7 of 8 waves instead of thrashing the 33.5KB stream.
    layer_step<IN0 + 0 * NOPS, 72>(Wd + WOFF[0], h);  __syncthreads();
    layer_step<IN0 + 1 * NOPS, 63>(Wd + WOFF[1], h);  __syncthreads();
    layer_step<IN0 + 2 * NOPS, 54>(Wd + WOFF[2], h);  __syncthreads();
    layer_step<IN0 + 3 * NOPS, 45>(Wd + WOFF[3], h);  __syncthreads();
    layer_step<IN0 + 4 * NOPS, 36>(Wd + WOFF[4], h);  __syncthreads();
    layer_step<IN0 + 5 * NOPS, 27>(Wd + WOFF[5], h);  __syncthreads();
    layer_step<IN0 + 6 * NOPS, 18>(Wd + WOFF[6], h);  __syncthreads();
    layer_step<IN0 + 7 * NOPS,  9>(Wd + WOFF[7], h);

    // Final dot stays unrolled: h indices must remain static (any dynamic h
    // access would force the whole array to scratch).
    const double* Wf = Wd + WOFF[8];
    double acc = 0.0;
    #pragma unroll
    for (int k = 0; k < FDIM; ++k) {
        acc = fma(Wf[k], h[k], acc);
    }
    if (active) out[row] = (float)acc;
}

extern "C" void kernel_launch(void* const* d_in, const int* in_sizes, int n_in,
                              void* d_out, int out_size, void* d_ws, size_t ws_size,
                              hipStream_t stream) {
    const float* x = (const float*)d_in[0];
    double* Wd     = (double*)d_ws;   // 4188 doubles = 33.5 KB
    float* out     = (float*)d_out;

    // widen weights (d_ws is re-poisoned before every call -> must rewrite)
    {
        dim3 grid((923 + 255) / 256, 9);
        widen_kernel<<<grid, 256, 0, stream>>>(
            (const float*)d_in[1], (const float*)d_in[2], (const float*)d_in[3],
            (const float*)d_in[4], (const float*)d_in[5], (const float*)d_in[6],
            (const float*)d_in[7], (const float*)d_in[8], (const float*)d_in[9],
            Wd);
    }

    int nrows = in_sizes[0] / IN0;
    int block = BDIM;
    int grid  = (nrows + block - 1) / block;
    net_kernel<<<grid, block, 0, stream>>>(x, Wd, out, nrows);
}